// Round 2
// baseline (3649.781 us; speedup 1.0000x reference)
//
#include <hip/hip_runtime.h>
#include <hip/hip_bf16.h>

#define NN 384
#define DP 128
#define NHEAD 4
#define CH 32
#define HCC 128

typedef __hip_bfloat16 bf16;

__device__ __forceinline__ float b2f(bf16 x){ return __bfloat162float(x); }
__device__ __forceinline__ bf16 f2b(float x){ return __float2bfloat16(x); }

// Kernel A: LayerNorm over d_pair + triangle bias (bias[h,q,k] independent of i)
__global__ __launch_bounds__(128) void ln_bias_kernel(
    const float* __restrict__ Zr, const float* __restrict__ lnw,
    const float* __restrict__ lnb, const float* __restrict__ Wb,
    bf16* __restrict__ Zn, float* __restrict__ bias)
{
  int pos = blockIdx.x;          // q*NN + k
  int t = threadIdx.x;           // 0..127 = channel d
  size_t base = (size_t)pos * DP;
  float x = Zr[base + t];
  float s = x, s2 = x * x;
  for (int m = 1; m < 64; m <<= 1){ s += __shfl_xor(s, m); s2 += __shfl_xor(s2, m); }
  __shared__ float red[4];
  int wv = t >> 6;
  if ((t & 63) == 0){ red[wv] = s; red[2 + wv] = s2; }
  __syncthreads();
  float mean = (red[0] + red[1]) * (1.0f / DP);
  float var  = (red[2] + red[3]) * (1.0f / DP) - mean * mean;
  float z = (x - mean) * rsqrtf(var + 1e-5f) * lnw[t] + lnb[t];
  Zn[base + t] = f2b(z);
  __shared__ float zsh[DP];
  zsh[t] = z;
  __syncthreads();
  if (t < NHEAD){
    float acc = 0.f;
    for (int d = 0; d < DP; d++) acc += zsh[d] * Wb[d * NHEAD + t];
    bias[(size_t)t * NN * NN + pos] = acc;   // layout [h][q*NN+k]
  }
}

// Kernel B: per (i, head): qkv projection into LDS, then softmax attention
__global__ __launch_bounds__(256) void attn_kernel(
    const bf16* __restrict__ Zn, const float* __restrict__ Wqkv,
    const float* __restrict__ Zm, const float* __restrict__ bias,
    bf16* __restrict__ wa)
{
  __shared__ bf16 qs[NN * CH];
  __shared__ bf16 ks[NN * CH];
  __shared__ bf16 vs[NN * CH];
  __shared__ float wbuf[4][NN];
  __shared__ float maskb[NN];

  int i = blockIdx.x >> 2;
  int h = blockIdx.x & 3;
  int t = threadIdx.x;

  for (int k = t; k < NN; k += 256)
    maskb[k] = (Zm[(size_t)i * NN + k] - 1.0f) * 1e9f;

  const float qscale = 0.17677669529663687f; // 1/sqrt(32)
  // projection: q,k,v [384 x 32] for this head
  for (int o = t; o < 3 * NN * CH; o += 256){
    int mat = o / (NN * CH);
    int rem = o - mat * (NN * CH);
    int n = rem >> 5;
    int c = rem & 31;
    int col = mat * HCC + h * CH + c;
    const bf16* zrow = Zn + (size_t)(i * NN + n) * DP;
    float acc = 0.f;
    for (int d = 0; d < DP; d++)
      acc += b2f(zrow[d]) * Wqkv[d * (3 * HCC) + col];
    if (mat == 0)      qs[rem] = f2b(acc * qscale);
    else if (mat == 1) ks[rem] = f2b(acc);
    else               vs[rem] = f2b(acc);
  }
  __syncthreads();

  int wv = t >> 6, ln = t & 63;
  const float* brow_base = bias + (size_t)h * NN * NN;
  for (int qr = wv; qr < NN; qr += 4){   // uniform trip count (96) for all 4 waves
    float qv[CH];
    #pragma unroll
    for (int c = 0; c < CH; c++) qv[c] = b2f(qs[qr * CH + c]);
    float lg[6];
    #pragma unroll
    for (int kk = 0; kk < 6; kk++){
      int k = ln + kk * 64;
      float acc = 0.f;
      #pragma unroll
      for (int c = 0; c < CH; c++) acc += qv[c] * b2f(ks[k * CH + c]);
      lg[kk] = acc + brow_base[qr * NN + k] + maskb[k];
    }
    float mx = lg[0];
    #pragma unroll
    for (int kk = 1; kk < 6; kk++) mx = fmaxf(mx, lg[kk]);
    for (int m = 1; m < 64; m <<= 1) mx = fmaxf(mx, __shfl_xor(mx, m));
    float ssum = 0.f;
    #pragma unroll
    for (int kk = 0; kk < 6; kk++){ lg[kk] = __expf(lg[kk] - mx); ssum += lg[kk]; }
    for (int m = 1; m < 64; m <<= 1) ssum += __shfl_xor(ssum, m);
    float inv = 1.0f / ssum;
    #pragma unroll
    for (int kk = 0; kk < 6; kk++) wbuf[wv][ln + kk * 64] = lg[kk];
    __syncthreads();
    int c = ln & 31, half = ln >> 5;
    float acc = 0.f;
    for (int k = half * 192; k < half * 192 + 192; k++)
      acc += wbuf[wv][k] * b2f(vs[k * CH + c]);
    acc += __shfl_xor(acc, 32);
    if (ln < 32)
      wa[(size_t)(i * NN + qr) * HCC + h * CH + c] = f2b(acc * inv);
    __syncthreads();
  }
}

// Kernel C: gate = sigmoid(Zn@Wg + gb); out = (gate*wa)@Wo + Z_raw + out_bias
__global__ __launch_bounds__(128) void out_kernel(
    const float* __restrict__ Zr, const bf16* __restrict__ Zn,
    const bf16* __restrict__ wa, const float* __restrict__ Wg,
    const float* __restrict__ gb, const float* __restrict__ Wo,
    const float* __restrict__ ob, float* __restrict__ out)
{
  __shared__ float zsh[DP];
  __shared__ float gw[HCC];
  int pos = blockIdx.x, t = threadIdx.x;
  size_t base = (size_t)pos * DP;
  zsh[t] = b2f(Zn[base + t]);
  __syncthreads();
  float acc = 0.f;
  for (int d = 0; d < DP; d++) acc += zsh[d] * Wg[d * HCC + t];
  float g = 1.0f / (1.0f + __expf(-(acc + gb[t])));
  gw[t] = g * b2f(wa[base + t]);
  __syncthreads();
  float o = 0.f;
  for (int e = 0; e < HCC; e++) o += gw[e] * Wo[e * DP + t];
  out[base + t] = Zr[base + t] + o + ob[t];
}

extern "C" void kernel_launch(void* const* d_in, const int* in_sizes, int n_in,
                              void* d_out, int out_size, void* d_ws, size_t ws_size,
                              hipStream_t stream)
{
  const float* Zr   = (const float*)d_in[0];
  const float* Zm   = (const float*)d_in[1];
  const float* lnw  = (const float*)d_in[2];
  const float* lnb  = (const float*)d_in[3];
  const float* Wb   = (const float*)d_in[4];
  const float* Wqkv = (const float*)d_in[5];
  const float* Wg   = (const float*)d_in[6];
  const float* gb   = (const float*)d_in[7];
  const float* Wo   = (const float*)d_in[8];
  const float* ob   = (const float*)d_in[9];
  float* out = (float*)d_out;

  char* ws = (char*)d_ws;
  // ws layout: Zn bf16 [NN*NN*DP] | bias fp32 [NHEAD*NN*NN] | wa bf16 [NN*NN*HCC]
  bf16*  Zn   = (bf16*)ws;
  float* bias = (float*)(ws + (size_t)NN * NN * DP * 2);
  bf16*  wa   = (bf16*)(ws + (size_t)NN * NN * DP * 2 + (size_t)NHEAD * NN * NN * 4);

  ln_bias_kernel<<<NN * NN, 128, 0, stream>>>(Zr, lnw, lnb, Wb, Zn, bias);
  attn_kernel<<<NN * NHEAD, 256, 0, stream>>>(Zn, Wqkv, Zm, bias, wa);
  out_kernel<<<NN * NN, 128, 0, stream>>>(Zr, Zn, wa, Wg, gb, Wo, ob, out);
}

// Round 3
// 1060.076 us; speedup vs baseline: 3.4429x; 3.4429x over previous
//
#include <hip/hip_runtime.h>
#include <hip/hip_bf16.h>

#define NN 384
#define DP 128
#define NHEAD 4
#define CH 32
#define HCC 128

typedef __hip_bfloat16 bf16;
typedef __bf16 bf16x8 __attribute__((ext_vector_type(8)));
typedef float floatx4 __attribute__((ext_vector_type(4)));

#define QKSTRIDE 40   // qs/ks row stride in bf16 elems (16B-aligned rows, 2-way banks)
#define VPSTRIDE 408  // vs/ps row stride in bf16 elems (16B-aligned rows, 2-way banks)

__device__ __forceinline__ float b2f(bf16 x){ return __bfloat162float(x); }
__device__ __forceinline__ bf16 f2b(float x){ return __float2bfloat16(x); }

// Prep: Wt[col][d] = bf16(Wqkv[d][col]); col in [0,384), d in [0,128)
__global__ __launch_bounds__(256) void wt_kernel(
    const float* __restrict__ Wqkv, __bf16* __restrict__ Wt)
{
  int idx = blockIdx.x * 256 + threadIdx.x;   // 49152 total
  int d = idx / NN, col = idx - d * NN;
  Wt[col * DP + d] = (__bf16)Wqkv[idx];
}

// Kernel A: LayerNorm over d_pair + triangle bias (bias[h,q,k] independent of i)
__global__ __launch_bounds__(128) void ln_bias_kernel(
    const float* __restrict__ Zr, const float* __restrict__ lnw,
    const float* __restrict__ lnb, const float* __restrict__ Wb,
    bf16* __restrict__ Zn, float* __restrict__ bias)
{
  int pos = blockIdx.x;          // q*NN + k
  int t = threadIdx.x;           // 0..127 = channel d
  size_t base = (size_t)pos * DP;
  float x = Zr[base + t];
  float s = x, s2 = x * x;
  for (int m = 1; m < 64; m <<= 1){ s += __shfl_xor(s, m); s2 += __shfl_xor(s2, m); }
  __shared__ float red[4];
  int wv = t >> 6;
  if ((t & 63) == 0){ red[wv] = s; red[2 + wv] = s2; }
  __syncthreads();
  float mean = (red[0] + red[1]) * (1.0f / DP);
  float var  = (red[2] + red[3]) * (1.0f / DP) - mean * mean;
  float z = (x - mean) * rsqrtf(var + 1e-5f) * lnw[t] + lnb[t];
  Zn[base + t] = f2b(z);
  __shared__ float zsh[DP];
  zsh[t] = z;
  __syncthreads();
  if (t < NHEAD){
    float acc = 0.f;
    for (int d = 0; d < DP; d++) acc += zsh[d] * Wb[d * NHEAD + t];
    bias[(size_t)t * NN * NN + pos] = acc;   // layout [h][q*NN+k]
  }
}

// Kernel B: per (i, head): MFMA qkv projection + MFMA flash attention
__global__ __launch_bounds__(256, 1) void attn_kernel(
    const __bf16* __restrict__ Zn, const __bf16* __restrict__ Wt,
    const float* __restrict__ Zm, const float* __restrict__ bias,
    __bf16* __restrict__ wa)
{
  __shared__ __align__(16) __bf16 qs[NN * QKSTRIDE];       // q: [row][c]
  __shared__ __align__(16) __bf16 ks[NN * QKSTRIDE];       // k: [row][c]
  __shared__ __align__(16) __bf16 vs[CH * VPSTRIDE];       // v^T: [c][row]
  __shared__ __align__(16) __bf16 ps[4 * 16 * VPSTRIDE];   // per-wave P strip [16][384]
  __shared__ float maskb[NN];

  int i = blockIdx.x >> 2;
  int h = blockIdx.x & 3;
  int t = threadIdx.x;
  int wv = t >> 6;
  int lane = t & 63;
  int m16 = lane & 15;       // low-16 lane id
  int quad = lane >> 4;      // 0..3

  for (int k = t; k < NN; k += 256)
    maskb[k] = (Zm[(size_t)i * NN + k] - 1.0f) * 1e9f;

  const float qscale = 0.17677669529663687f; // 1/sqrt(32)

  // ---- Phase 1: qkv projection via MFMA ----
  // out tile grid: M = 384 (24 mtiles), N = 96 (6 ntiles: q0 q1 k0 k1 v0 v1), K = 128
  for (int mt = wv * 6; mt < wv * 6 + 6; mt++){
    bf16x8 afr[4];
    const __bf16* arow = Zn + (size_t)(i * NN + mt * 16 + m16) * DP + quad * 8;
    #pragma unroll
    for (int kc = 0; kc < 4; kc++) afr[kc] = *(const bf16x8*)(arow + kc * 32);
    for (int nt = 0; nt < 6; nt++){
      int mat = nt >> 1;
      int colbase = mat * HCC + h * CH + (nt & 1) * 16;
      const __bf16* brow = Wt + (size_t)(colbase + m16) * DP + quad * 8;
      floatx4 acc = {0.f, 0.f, 0.f, 0.f};
      #pragma unroll
      for (int kc = 0; kc < 4; kc++){
        bf16x8 bfr = *(const bf16x8*)(brow + kc * 32);
        acc = __builtin_amdgcn_mfma_f32_16x16x32_bf16(afr[kc], bfr, acc, 0, 0, 0);
      }
      // D layout: col = m16, row(in tile) = quad*4 + reg
      int ccol = (nt & 1) * 16 + m16;   // 0..31 within head
      #pragma unroll
      for (int reg = 0; reg < 4; reg++){
        int row = mt * 16 + quad * 4 + reg;
        float v = acc[reg];
        if (mat == 0)      qs[row * QKSTRIDE + ccol] = (__bf16)(v * qscale);
        else if (mat == 1) ks[row * QKSTRIDE + ccol] = (__bf16)v;
        else               vs[ccol * VPSTRIDE + row] = (__bf16)v;
      }
    }
  }
  __syncthreads();

  // ---- Phase 2: attention, per-wave 16-row strips ----
  const float* brow_base = bias + (size_t)h * NN * NN;
  __bf16* pw = ps + wv * 16 * VPSTRIDE;

  for (int s = 0; s < 6; s++){
    int strip = wv * 6 + s;
    // S = Q_strip @ K^T : 24 independent MFMAs, K=32 in one shot
    bf16x8 qf = *(const bf16x8*)(qs + (strip * 16 + m16) * QKSTRIDE + quad * 8);
    floatx4 sacc[24];
    #pragma unroll
    for (int kt = 0; kt < 24; kt++){
      bf16x8 kf = *(const bf16x8*)(ks + (kt * 16 + m16) * QKSTRIDE + quad * 8);
      floatx4 z = {0.f, 0.f, 0.f, 0.f};
      sacc[kt] = __builtin_amdgcn_mfma_f32_16x16x32_bf16(qf, kf, z, 0, 0, 0);
    }
    // add bias + mask; row-wise max
    float mx[4] = {-1e30f, -1e30f, -1e30f, -1e30f};
    #pragma unroll
    for (int kt = 0; kt < 24; kt++){
      int col = kt * 16 + m16;
      float mb = maskb[col];
      #pragma unroll
      for (int reg = 0; reg < 4; reg++){
        int row = strip * 16 + quad * 4 + reg;
        float v = sacc[kt][reg] + brow_base[(size_t)row * NN + col] + mb;
        sacc[kt][reg] = v;
        mx[reg] = fmaxf(mx[reg], v);
      }
    }
    #pragma unroll
    for (int reg = 0; reg < 4; reg++)
      for (int msk = 1; msk < 16; msk <<= 1)
        mx[reg] = fmaxf(mx[reg], __shfl_xor(mx[reg], msk));
    // exp + row sum + write P (bf16) to per-wave LDS strip
    float sm[4] = {0.f, 0.f, 0.f, 0.f};
    #pragma unroll
    for (int kt = 0; kt < 24; kt++){
      int col = kt * 16 + m16;
      #pragma unroll
      for (int reg = 0; reg < 4; reg++){
        float p = __expf(sacc[kt][reg] - mx[reg]);
        sm[reg] += p;
        pw[(quad * 4 + reg) * VPSTRIDE + col] = (__bf16)p;
      }
    }
    #pragma unroll
    for (int reg = 0; reg < 4; reg++)
      for (int msk = 1; msk < 16; msk <<= 1)
        sm[reg] += __shfl_xor(sm[reg], msk);
    float inv[4];
    #pragma unroll
    for (int reg = 0; reg < 4; reg++) inv[reg] = 1.0f / sm[reg];

    // PV: P(16x384) @ V(384x32), A-frags from pw, B-frags from vs (v^T)
    floatx4 oacc[2] = {{0.f,0.f,0.f,0.f},{0.f,0.f,0.f,0.f}};
    #pragma unroll
    for (int kc = 0; kc < 12; kc++){
      bf16x8 pa = *(const bf16x8*)(pw + m16 * VPSTRIDE + kc * 32 + quad * 8);
      #pragma unroll
      for (int ct = 0; ct < 2; ct++){
        bf16x8 vb = *(const bf16x8*)(vs + (ct * 16 + m16) * VPSTRIDE + kc * 32 + quad * 8);
        oacc[ct] = __builtin_amdgcn_mfma_f32_16x16x32_bf16(pa, vb, oacc[ct], 0, 0, 0);
      }
    }
    // store wa strip: row = strip*16+quad*4+reg, col = h*32 + ct*16 + m16
    #pragma unroll
    for (int ct = 0; ct < 2; ct++){
      #pragma unroll
      for (int reg = 0; reg < 4; reg++){
        int row = strip * 16 + quad * 4 + reg;
        wa[(size_t)(i * NN + row) * HCC + h * CH + ct * 16 + m16] =
            (__bf16)(oacc[ct][reg] * inv[reg]);
      }
    }
  }
}

// Kernel C: gate = sigmoid(Zn@Wg + gb); out = (gate*wa)@Wo + Z_raw + out_bias
__global__ __launch_bounds__(128) void out_kernel(
    const float* __restrict__ Zr, const bf16* __restrict__ Zn,
    const bf16* __restrict__ wa, const float* __restrict__ Wg,
    const float* __restrict__ gb, const float* __restrict__ Wo,
    const float* __restrict__ ob, float* __restrict__ out)
{
  __shared__ float zsh[DP];
  __shared__ float gw[HCC];
  int pos = blockIdx.x, t = threadIdx.x;
  size_t base = (size_t)pos * DP;
  zsh[t] = b2f(Zn[base + t]);
  __syncthreads();
  float acc = 0.f;
  for (int d = 0; d < DP; d++) acc += zsh[d] * Wg[d * HCC + t];
  float g = 1.0f / (1.0f + __expf(-(acc + gb[t])));
  gw[t] = g * b2f(wa[base + t]);
  __syncthreads();
  float o = 0.f;
  for (int e = 0; e < HCC; e++) o += gw[e] * Wo[e * DP + t];
  out[base + t] = Zr[base + t] + o + ob[t];
}

extern "C" void kernel_launch(void* const* d_in, const int* in_sizes, int n_in,
                              void* d_out, int out_size, void* d_ws, size_t ws_size,
                              hipStream_t stream)
{
  const float* Zr   = (const float*)d_in[0];
  const float* Zm   = (const float*)d_in[1];
  const float* lnw  = (const float*)d_in[2];
  const float* lnb  = (const float*)d_in[3];
  const float* Wb   = (const float*)d_in[4];
  const float* Wqkv = (const float*)d_in[5];
  const float* Wg   = (const float*)d_in[6];
  const float* gb   = (const float*)d_in[7];
  const float* Wo   = (const float*)d_in[8];
  const float* ob   = (const float*)d_in[9];
  float* out = (float*)d_out;

  char* ws = (char*)d_ws;
  // ws: Zn bf16 [NN*NN*DP] | bias fp32 [NHEAD*NN*NN] | wa bf16 [NN*NN*HCC] | Wt bf16 [384*128]
  bf16*   Zn   = (bf16*)ws;
  float*  bias = (float*)(ws + (size_t)NN * NN * DP * 2);
  bf16*   wa   = (bf16*)(ws + (size_t)NN * NN * DP * 2 + (size_t)NHEAD * NN * NN * 4);
  __bf16* Wt   = (__bf16*)(ws + (size_t)NN * NN * DP * 2 + (size_t)NHEAD * NN * NN * 4
                              + (size_t)NN * NN * HCC * 2);

  wt_kernel<<<(3 * HCC * DP) / 256, 256, 0, stream>>>(Wqkv, Wt);
  ln_bias_kernel<<<NN * NN, 128, 0, stream>>>(Zr, lnw, lnb, Wb, Zn, bias);
  attn_kernel<<<NN * NHEAD, 256, 0, stream>>>((const __bf16*)Zn, Wt, Zm, bias, (__bf16*)wa);
  out_kernel<<<NN * NN, 128, 0, stream>>>(Zr, Zn, wa, Wg, gb, Wo, ob, out);
}

// Round 4
// 493.472 us; speedup vs baseline: 7.3961x; 2.1482x over previous
//
#include <hip/hip_runtime.h>
#include <hip/hip_bf16.h>

#define NN 384
#define DP 128
#define NHEAD 4
#define CH 32
#define HCC 128

typedef __hip_bfloat16 bf16;
typedef __bf16 bf16x8 __attribute__((ext_vector_type(8)));
typedef __bf16 bf16x4 __attribute__((ext_vector_type(4)));
typedef float floatx4 __attribute__((ext_vector_type(4)));

#define QKSTRIDE 40   // qs/ks row stride in bf16 elems
#define VPSTRIDE 408  // vs/ps row stride in bf16 elems
#define WSTRIDE 136   // weight/G-strip stride in bf16 elems (conflict-free b128)

__device__ __forceinline__ float b2f(bf16 x){ return __bfloat162float(x); }
__device__ __forceinline__ bf16 f2b(float x){ return __float2bfloat16(x); }

// Prep: Wt[col][d] = bf16(Wqkv[d][col]); col in [0,384), d in [0,128)
__global__ __launch_bounds__(256) void wt_kernel(
    const float* __restrict__ Wqkv, __bf16* __restrict__ Wt)
{
  int idx = blockIdx.x * 256 + threadIdx.x;   // 49152 total
  int d = idx / NN, col = idx - d * NN;
  Wt[col * DP + d] = (__bf16)Wqkv[idx];
}

// Prep: WgT[h][d] = Wg[d][h]; WoT[d][e] = Wo[e][d]  (both 128x128)
__global__ __launch_bounds__(256) void wgo_kernel(
    const float* __restrict__ Wg, const float* __restrict__ Wo,
    __bf16* __restrict__ WgT, __bf16* __restrict__ WoT)
{
  int idx = blockIdx.x * 256 + threadIdx.x;   // 16384 total
  int r = idx >> 7, c = idx & 127;
  WgT[idx] = (__bf16)Wg[c * 128 + r];
  WoT[idx] = (__bf16)Wo[c * 128 + r];
}

// Kernel A: LayerNorm + triangle bias. 32-lane group per position, float4 lanes.
__global__ __launch_bounds__(256) void ln_bias_kernel(
    const float* __restrict__ Zr, const float* __restrict__ lnw,
    const float* __restrict__ lnb, const float* __restrict__ Wb,
    bf16* __restrict__ Zn, float* __restrict__ bias)
{
  int t = threadIdx.x;
  int grp = t >> 5, lane32 = t & 31;
  int pos = blockIdx.x * 8 + grp;
  size_t base = (size_t)pos * DP;
  const float4 x = *(const float4*)(Zr + base + lane32 * 4);
  float s  = x.x + x.y + x.z + x.w;
  float s2 = x.x*x.x + x.y*x.y + x.z*x.z + x.w*x.w;
  #pragma unroll
  for (int m = 1; m < 32; m <<= 1){ s += __shfl_xor(s, m); s2 += __shfl_xor(s2, m); }
  float mean = s * (1.0f / DP);
  float var  = s2 * (1.0f / DP) - mean * mean;
  float rstd = rsqrtf(var + 1e-5f);
  const float4 w4 = *(const float4*)(lnw + lane32 * 4);
  const float4 b4 = *(const float4*)(lnb + lane32 * 4);
  float z0 = (x.x - mean) * rstd * w4.x + b4.x;
  float z1 = (x.y - mean) * rstd * w4.y + b4.y;
  float z2 = (x.z - mean) * rstd * w4.z + b4.z;
  float z3 = (x.w - mean) * rstd * w4.w + b4.w;
  bf16x4 zb = { (__bf16)z0, (__bf16)z1, (__bf16)z2, (__bf16)z3 };
  *(bf16x4*)((__bf16*)Zn + base + lane32 * 4) = zb;
  // bias partials: p[h] = sum_j z_j * Wb[(lane32*4+j)][h]
  const float4 wb0 = *(const float4*)(Wb + (lane32 * 4 + 0) * NHEAD);
  const float4 wb1 = *(const float4*)(Wb + (lane32 * 4 + 1) * NHEAD);
  const float4 wb2 = *(const float4*)(Wb + (lane32 * 4 + 2) * NHEAD);
  const float4 wb3 = *(const float4*)(Wb + (lane32 * 4 + 3) * NHEAD);
  float p0 = z0*wb0.x + z1*wb1.x + z2*wb2.x + z3*wb3.x;
  float p1 = z0*wb0.y + z1*wb1.y + z2*wb2.y + z3*wb3.y;
  float p2 = z0*wb0.z + z1*wb1.z + z2*wb2.z + z3*wb3.z;
  float p3 = z0*wb0.w + z1*wb1.w + z2*wb2.w + z3*wb3.w;
  #pragma unroll
  for (int m = 1; m < 32; m <<= 1){
    p0 += __shfl_xor(p0, m); p1 += __shfl_xor(p1, m);
    p2 += __shfl_xor(p2, m); p3 += __shfl_xor(p3, m);
  }
  if (lane32 == 0){
    bias[0 * NN * NN + pos] = p0;
    bias[1 * NN * NN + pos] = p1;
    bias[2 * NN * NN + pos] = p2;
    bias[3 * NN * NN + pos] = p3;
  }
}

// Kernel B: per (i, head): MFMA qkv projection + MFMA flash attention
__global__ __launch_bounds__(256, 1) void attn_kernel(
    const __bf16* __restrict__ Zn, const __bf16* __restrict__ Wt,
    const float* __restrict__ Zm, const float* __restrict__ bias,
    __bf16* __restrict__ wa)
{
  __shared__ __align__(16) __bf16 qs[NN * QKSTRIDE];       // q: [row][c]
  __shared__ __align__(16) __bf16 ks[NN * QKSTRIDE];       // k: [row][c]
  __shared__ __align__(16) __bf16 vs[CH * VPSTRIDE];       // v^T: [c][row]
  __shared__ __align__(16) __bf16 ps[4 * 16 * VPSTRIDE];   // per-wave P strip [16][384]
  __shared__ float maskb[NN];

  int i = blockIdx.x >> 2;
  int h = blockIdx.x & 3;
  int t = threadIdx.x;
  int wv = t >> 6;
  int lane = t & 63;
  int m16 = lane & 15;       // low-16 lane id
  int quad = lane >> 4;      // 0..3

  for (int k = t; k < NN; k += 256)
    maskb[k] = (Zm[(size_t)i * NN + k] - 1.0f) * 1e9f;

  const float qscale = 0.17677669529663687f; // 1/sqrt(32)

  // ---- Phase 1: qkv projection via MFMA ----
  for (int mt = wv * 6; mt < wv * 6 + 6; mt++){
    bf16x8 afr[4];
    const __bf16* arow = Zn + (size_t)(i * NN + mt * 16 + m16) * DP + quad * 8;
    #pragma unroll
    for (int kc = 0; kc < 4; kc++) afr[kc] = *(const bf16x8*)(arow + kc * 32);
    for (int nt = 0; nt < 6; nt++){
      int mat = nt >> 1;
      int colbase = mat * HCC + h * CH + (nt & 1) * 16;
      const __bf16* brow = Wt + (size_t)(colbase + m16) * DP + quad * 8;
      floatx4 acc = {0.f, 0.f, 0.f, 0.f};
      #pragma unroll
      for (int kc = 0; kc < 4; kc++){
        bf16x8 bfr = *(const bf16x8*)(brow + kc * 32);
        acc = __builtin_amdgcn_mfma_f32_16x16x32_bf16(afr[kc], bfr, acc, 0, 0, 0);
      }
      int ccol = (nt & 1) * 16 + m16;   // 0..31 within head
      #pragma unroll
      for (int reg = 0; reg < 4; reg++){
        int row = mt * 16 + quad * 4 + reg;
        float v = acc[reg];
        if (mat == 0)      qs[row * QKSTRIDE + ccol] = (__bf16)(v * qscale);
        else if (mat == 1) ks[row * QKSTRIDE + ccol] = (__bf16)v;
        else               vs[ccol * VPSTRIDE + row] = (__bf16)v;
      }
    }
  }
  __syncthreads();

  // ---- Phase 2: attention, per-wave 16-row strips ----
  const float* brow_base = bias + (size_t)h * NN * NN;
  __bf16* pw = ps + wv * 16 * VPSTRIDE;

  for (int s = 0; s < 6; s++){
    int strip = wv * 6 + s;
    bf16x8 qf = *(const bf16x8*)(qs + (strip * 16 + m16) * QKSTRIDE + quad * 8);
    floatx4 sacc[24];
    #pragma unroll
    for (int kt = 0; kt < 24; kt++){
      bf16x8 kf = *(const bf16x8*)(ks + (kt * 16 + m16) * QKSTRIDE + quad * 8);
      floatx4 z = {0.f, 0.f, 0.f, 0.f};
      sacc[kt] = __builtin_amdgcn_mfma_f32_16x16x32_bf16(qf, kf, z, 0, 0, 0);
    }
    float mx[4] = {-1e30f, -1e30f, -1e30f, -1e30f};
    #pragma unroll
    for (int kt = 0; kt < 24; kt++){
      int col = kt * 16 + m16;
      float mb = maskb[col];
      #pragma unroll
      for (int reg = 0; reg < 4; reg++){
        int row = strip * 16 + quad * 4 + reg;
        float v = sacc[kt][reg] + brow_base[(size_t)row * NN + col] + mb;
        sacc[kt][reg] = v;
        mx[reg] = fmaxf(mx[reg], v);
      }
    }
    #pragma unroll
    for (int reg = 0; reg < 4; reg++)
      for (int msk = 1; msk < 16; msk <<= 1)
        mx[reg] = fmaxf(mx[reg], __shfl_xor(mx[reg], msk));
    float sm[4] = {0.f, 0.f, 0.f, 0.f};
    #pragma unroll
    for (int kt = 0; kt < 24; kt++){
      int col = kt * 16 + m16;
      #pragma unroll
      for (int reg = 0; reg < 4; reg++){
        float p = __expf(sacc[kt][reg] - mx[reg]);
        sm[reg] += p;
        pw[(quad * 4 + reg) * VPSTRIDE + col] = (__bf16)p;
      }
    }
    #pragma unroll
    for (int reg = 0; reg < 4; reg++)
      for (int msk = 1; msk < 16; msk <<= 1)
        sm[reg] += __shfl_xor(sm[reg], msk);
    float inv[4];
    #pragma unroll
    for (int reg = 0; reg < 4; reg++) inv[reg] = 1.0f / sm[reg];

    floatx4 oacc[2] = {{0.f,0.f,0.f,0.f},{0.f,0.f,0.f,0.f}};
    #pragma unroll
    for (int kc = 0; kc < 12; kc++){
      bf16x8 pa = *(const bf16x8*)(pw + m16 * VPSTRIDE + kc * 32 + quad * 8);
      #pragma unroll
      for (int ct = 0; ct < 2; ct++){
        bf16x8 vb = *(const bf16x8*)(vs + (ct * 16 + m16) * VPSTRIDE + kc * 32 + quad * 8);
        oacc[ct] = __builtin_amdgcn_mfma_f32_16x16x32_bf16(pa, vb, oacc[ct], 0, 0, 0);
      }
    }
    #pragma unroll
    for (int ct = 0; ct < 2; ct++){
      #pragma unroll
      for (int reg = 0; reg < 4; reg++){
        int row = strip * 16 + quad * 4 + reg;
        wa[(size_t)(i * NN + row) * HCC + h * CH + ct * 16 + m16] =
            (__bf16)(oacc[ct][reg] * inv[reg]);
      }
    }
  }
}

// Kernel C (MFMA): gate = sigmoid(Zn@Wg + gb); out = (gate*wa)@Wo + Zr + ob
__global__ __launch_bounds__(256, 1) void out_kernel(
    const float* __restrict__ Zr, const __bf16* __restrict__ Zn,
    const __bf16* __restrict__ wa, const __bf16* __restrict__ WgT,
    const float* __restrict__ gb, const __bf16* __restrict__ WoT,
    const float* __restrict__ ob, float* __restrict__ out)
{
  __shared__ __align__(16) __bf16 wgs[128 * WSTRIDE];       // [h][d]
  __shared__ __align__(16) __bf16 wos[128 * WSTRIDE];       // [d][e]
  __shared__ __align__(16) __bf16 gsh[4][16 * WSTRIDE];     // per-wave G strip
  __shared__ float gbs[HCC], obs[DP];

  int t = threadIdx.x;
  int wv = t >> 6, lane = t & 63;
  int m16 = lane & 15, quad = lane >> 4;

  for (int idx = t * 8; idx < 128 * 128; idx += 256 * 8){
    int r = idx >> 7, c = idx & 127;
    *(bf16x8*)(wgs + r * WSTRIDE + c) = *(const bf16x8*)(WgT + idx);
    *(bf16x8*)(wos + r * WSTRIDE + c) = *(const bf16x8*)(WoT + idx);
  }
  if (t < 128){ gbs[t] = gb[t]; obs[t] = ob[t]; }
  __syncthreads();

  int mbase = blockIdx.x * 128;
  __bf16* gstrip = gsh[wv];

  for (int sp = 0; sp < 2; sp++){
    int row0 = mbase + (sp * 4 + wv) * 16;
    // gate GEMM: A from Zn rows, B from wgs
    bf16x8 afr[4];
    const __bf16* arow = Zn + (size_t)(row0 + m16) * DP + quad * 8;
    #pragma unroll
    for (int kc = 0; kc < 4; kc++) afr[kc] = *(const bf16x8*)(arow + kc * 32);
    #pragma unroll
    for (int nt = 0; nt < 8; nt++){
      floatx4 acc = {0.f, 0.f, 0.f, 0.f};
      #pragma unroll
      for (int kc = 0; kc < 4; kc++){
        bf16x8 bfr = *(const bf16x8*)(wgs + (nt * 16 + m16) * WSTRIDE + kc * 32 + quad * 8);
        acc = __builtin_amdgcn_mfma_f32_16x16x32_bf16(afr[kc], bfr, acc, 0, 0, 0);
      }
      int col = nt * 16 + m16;
      #pragma unroll
      for (int reg = 0; reg < 4; reg++){
        int row = row0 + quad * 4 + reg;
        float g = 1.0f / (1.0f + __expf(-(acc[reg] + gbs[col])));
        float w = __bfloat162float(wa[(size_t)row * HCC + col]);
        gstrip[(quad * 4 + reg) * WSTRIDE + col] = (__bf16)(g * w);
      }
    }
    // out GEMM: A from gstrip (same wave — lockstep, compiler inserts lgkmcnt waits)
    bf16x8 gfr[4];
    #pragma unroll
    for (int kc = 0; kc < 4; kc++)
      gfr[kc] = *(const bf16x8*)(gstrip + m16 * WSTRIDE + kc * 32 + quad * 8);
    #pragma unroll
    for (int nt = 0; nt < 8; nt++){
      floatx4 acc = {0.f, 0.f, 0.f, 0.f};
      #pragma unroll
      for (int kc = 0; kc < 4; kc++){
        bf16x8 bfr = *(const bf16x8*)(wos + (nt * 16 + m16) * WSTRIDE + kc * 32 + quad * 8);
        acc = __builtin_amdgcn_mfma_f32_16x16x32_bf16(gfr[kc], bfr, acc, 0, 0, 0);
      }
      int col = nt * 16 + m16;
      #pragma unroll
      for (int reg = 0; reg < 4; reg++){
        int row = row0 + quad * 4 + reg;
        size_t off = (size_t)row * DP + col;
        out[off] = Zr[off] + acc[reg] + obs[col];
      }
    }
  }
}

extern "C" void kernel_launch(void* const* d_in, const int* in_sizes, int n_in,
                              void* d_out, int out_size, void* d_ws, size_t ws_size,
                              hipStream_t stream)
{
  const float* Zr   = (const float*)d_in[0];
  const float* Zm   = (const float*)d_in[1];
  const float* lnw  = (const float*)d_in[2];
  const float* lnb  = (const float*)d_in[3];
  const float* Wb   = (const float*)d_in[4];
  const float* Wqkv = (const float*)d_in[5];
  const float* Wg   = (const float*)d_in[6];
  const float* gb   = (const float*)d_in[7];
  const float* Wo   = (const float*)d_in[8];
  const float* ob   = (const float*)d_in[9];
  float* out = (float*)d_out;

  char* ws = (char*)d_ws;
  // ws: Zn bf16 | bias fp32 | wa bf16 | Wt bf16 | WgT bf16 | WoT bf16
  size_t off = 0;
  bf16*   Zn   = (bf16*)(ws + off);           off += (size_t)NN * NN * DP * 2;
  float*  bias = (float*)(ws + off);          off += (size_t)NHEAD * NN * NN * 4;
  bf16*   wa   = (bf16*)(ws + off);           off += (size_t)NN * NN * HCC * 2;
  __bf16* Wt   = (__bf16*)(ws + off);         off += (size_t)3 * HCC * DP * 2;
  __bf16* WgT  = (__bf16*)(ws + off);         off += (size_t)DP * HCC * 2;
  __bf16* WoT  = (__bf16*)(ws + off);         off += (size_t)HCC * DP * 2;

  wt_kernel<<<(3 * HCC * DP) / 256, 256, 0, stream>>>(Wqkv, Wt);
  wgo_kernel<<<(DP * HCC) / 256, 256, 0, stream>>>(Wg, Wo, WgT, WoT);
  ln_bias_kernel<<<NN * NN / 8, 256, 0, stream>>>(Zr, lnw, lnb, Wb, Zn, bias);
  attn_kernel<<<NN * NHEAD, 256, 0, stream>>>((const __bf16*)Zn, Wt, Zm, bias, (__bf16*)wa);
  out_kernel<<<NN * NN / 128, 256, 0, stream>>>(Zr, (const __bf16*)Zn, (const __bf16*)wa,
                                                WgT, gb, WoT, ob, out);
}